// Round 18
// baseline (288.238 us; speedup 1.0000x reference)
//
#include <hip/hip_runtime.h>
#include <hip/hip_bf16.h>
#include <math.h>

#define N_ROWS   131072   // 8*16384
#define DIMS     64
#define NCODES   1024
#define DECAY    0.99f
#define EPSF     1e-5f
#define BAND     2e-3f    // approx-gap band; eps_approx ~2e-4, 5x margin

// d_out layout (float32 elements)
#define OFF_ZQ    0
#define OFF_IDX   8388608
#define OFF_LOSS  8519680
#define OFF_PERP  8519681
#define OFF_EMB   8519682
#define OFF_ECS   8585218
#define OFF_EMAW  8586242

typedef unsigned int uint;
typedef short bf16x8 __attribute__((ext_vector_type(8)));
typedef float f32x4  __attribute__((ext_vector_type(4)));

__device__ __forceinline__ void atomic_add_f32_nr(float* p, float v) {
  // no return use -> fire-and-forget global_atomic_add (no wave stall)
  __hip_atomic_fetch_add(p, v, __ATOMIC_RELAXED, __HIP_MEMORY_SCOPE_AGENT);
}

__device__ __forceinline__ unsigned short bf16_rne(float f) {
  uint u = __float_as_uint(f);
  uint r = u + 0x7fffu + ((u >> 16) & 1u);
  return (unsigned short)(r >> 16);
}
__device__ __forceinline__ float bf16_f32(unsigned short h) {
  return __uint_as_float(((uint)h) << 16);
}

// numpy pairwise_sum base case (n=64): 8 strided accumulators, tree combine.
__device__ __forceinline__ float np_pairwise64_sq(const float* v) {
#pragma clang fp contract(off)
  float r[8];
#pragma unroll
  for (int j = 0; j < 8; ++j) r[j] = v[j] * v[j];
#pragma unroll
  for (int i = 8; i < 64; i += 8)
#pragma unroll
    for (int j = 0; j < 8; ++j) r[j] += v[i + j] * v[i + j];
  return ((r[0] + r[1]) + (r[2] + r[3])) + ((r[4] + r[5]) + (r[6] + r[7]));
}

// ---------------- K0m: merged init + pack (grid 64) ------------------------
__global__ __launch_bounds__(256) void k0m(const float* __restrict__ emb,
                                           float* __restrict__ ee,
                                           uint* __restrict__ cluster,
                                           uint* __restrict__ cnt,
                                           bf16x8* __restrict__ bsplit,
                                           float* __restrict__ dw) {
  int T = blockIdx.x;
  int t = threadIdx.x;
  int gid = T * 256 + t;               // 16384 threads
  for (int i = gid; i < NCODES * DIMS; i += 16384) dw[i] = 0.0f;

  int l = t & 63;
  int slot = t >> 6;                   // 0..3 = (ktile<<1)|split
  int ktile = slot >> 1, split = slot & 1;
  int code = T * 16 + (l & 15);
  int k0 = ktile * 32 + ((l >> 4) << 3);
  const float* ep = emb + (size_t)code * DIMS + k0;
  float4 fa = *(const float4*)ep;
  float4 fb = *(const float4*)(ep + 4);
  float fs[8] = {fa.x, fa.y, fa.z, fa.w, fb.x, fb.y, fb.z, fb.w};
  bf16x8 v;
#pragma unroll
  for (int i = 0; i < 8; ++i) {
    unsigned short h = bf16_rne(fs[i]);
    if (split == 0) v[i] = (short)h;
    else            v[i] = (short)bf16_rne(fs[i] - bf16_f32(h));
  }
  bsplit[(size_t)((T * 2 + ktile) * 2 + split) * 64 + l] = v;

  if (t < 16) {
    int c = T * 16 + t;
    float ev[DIMS];
    const float4* e4 = (const float4*)(emb + (size_t)c * DIMS);
#pragma unroll
    for (int i = 0; i < 16; ++i) {
      float4 w = e4[i];
      ev[4*i] = w.x; ev[4*i+1] = w.y; ev[4*i+2] = w.z; ev[4*i+3] = w.w;
    }
    ee[c] = np_pairwise64_sq(ev);
  } else if (t < 32) {
    cluster[T * 16 + (t - 16)] = 0u;
  }
  if (T == 0 && t == 32) *cnt = 0u;
}

// ---------------- K1: MFMA argmin + fused zq/loss/dw epilogue --------------
// Round-13 structure (best measured) + dw accumulated here via fire-and-
// forget f32 atomics (round-18: the sort-based dw pipeline [prefix+scatter+
// segmented-sum] existed to avoid these atomics, but round-5's "atomics are
// slow" was confounded by a same-address f64 atomic [proven round 7]; the
// dw atomics alone are ~14-25us of L2 work overlapped with compute, and
// deleting k3c+k3d removes 2 launches + ~30us from the serial tail chain).
__global__ __launch_bounds__(256) void k1_mfma(const float* __restrict__ z,
                                               const float* __restrict__ emb,
                                               const bf16x8* __restrict__ bsplit,
                                               const float* __restrict__ ee,
                                               int* __restrict__ idx_out,
                                               float* __restrict__ idx_f_out,
                                               float* __restrict__ out_zq,
                                               double* __restrict__ sqpart,
                                               uint* __restrict__ cluster,
                                               float* __restrict__ dw,
                                               uint* __restrict__ cnt,
                                               uint* __restrict__ list) {
  __shared__ bf16x8 btile[2][256];     // 8KB: [tile parity][frag*64+lane]
  __shared__ float  eel[NCODES];       // 4KB
  __shared__ int    sidx[64];
  __shared__ double wred[4];
  int t = threadIdx.x;
  int l = t & 63;
  int w = t >> 6;
  int rowbase = blockIdx.x * 64 + w * 16;
  int arow = rowbase + (l & 15);
  int kq = (l >> 4) << 3;              // 0,8,16,24
  int col = l & 15;

  for (int i = t; i < NCODES; i += 256) eel[i] = ee[i];

  // A fragments: z row split into bf16 hi/mid, pre-scaled by -2 (exact).
  bf16x8 ahi[2], ami[2];
#pragma unroll
  for (int t2 = 0; t2 < 2; ++t2) {
    const float* zp = z + (size_t)arow * DIMS + t2 * 32 + kq;
    float4 fa = *(const float4*)zp;
    float4 fb = *(const float4*)(zp + 4);
    float fs[8] = {fa.x, fa.y, fa.z, fa.w, fb.x, fb.y, fb.z, fb.w};
#pragma unroll
    for (int i = 0; i < 8; ++i) {
      unsigned short h = bf16_rne(fs[i]);
      float m = fs[i] - bf16_f32(h);
      ahi[t2][i] = (short)bf16_rne(-2.0f * fs[i]);  // == -2*hi
      ami[t2][i] = (short)bf16_rne(-2.0f * m);      // == -2*mid
    }
  }

  float best[4]  = {3.4e38f, 3.4e38f, 3.4e38f, 3.4e38f};
  float second[4] = {3.4e38f, 3.4e38f, 3.4e38f, 3.4e38f};
  int   bidx[4] = {0, 0, 0, 0};

  // prefetch tiles 0,1 (frag w of each)
  bf16x8 vp0 = bsplit[(size_t)(0 * 4 + w) * 64 + l];
  bf16x8 vp1 = bsplit[(size_t)(1 * 4 + w) * 64 + l];

  for (int T = 0; T < 64; T += 2) {
    __syncthreads();                   // prior reads done; prefetch landed
    btile[0][w * 64 + l] = vp0;
    btile[1][w * 64 + l] = vp1;
    __syncthreads();                   // stores visible
    if (T + 2 < 64) {                  // issue NEXT prefetch *after* barrier:
      vp0 = bsplit[(size_t)((T + 2) * 4 + w) * 64 + l];  // in flight during
      vp1 = bsplit[(size_t)((T + 3) * 4 + w) * 64 + l];  // compute below
    }

#pragma unroll
    for (int u = 0; u < 2; ++u) {
      int code = (T + u) * 16 + col;
      float eeT = eel[code];
      bf16x8 bhi0 = btile[u][0 * 64 + l];
      bf16x8 bmi0 = btile[u][1 * 64 + l];
      bf16x8 bhi1 = btile[u][2 * 64 + l];
      bf16x8 bmi1 = btile[u][3 * 64 + l];

      f32x4 acc = {eeT, eeT, eeT, eeT};  // C-seed: s = ee - 2*dot
      acc = __builtin_amdgcn_mfma_f32_16x16x32_bf16(ahi[0], bhi0, acc, 0, 0, 0);
      acc = __builtin_amdgcn_mfma_f32_16x16x32_bf16(ahi[1], bhi1, acc, 0, 0, 0);
      acc = __builtin_amdgcn_mfma_f32_16x16x32_bf16(ahi[0], bmi0, acc, 0, 0, 0);
      acc = __builtin_amdgcn_mfma_f32_16x16x32_bf16(ahi[1], bmi1, acc, 0, 0, 0);
      acc = __builtin_amdgcn_mfma_f32_16x16x32_bf16(ami[0], bhi0, acc, 0, 0, 0);
      acc = __builtin_amdgcn_mfma_f32_16x16x32_bf16(ami[1], bhi1, acc, 0, 0, 0);

#pragma unroll
      for (int j = 0; j < 4; ++j) {
        float s = acc[j];
        bool lt = s < best[j];
        second[j] = lt ? best[j] : fminf(second[j], s);
        best[j]   = lt ? s : best[j];
        bidx[j]   = lt ? code : bidx[j];
      }
    }
  }

  // reduce (best, second, idx) across the 16 lanes sharing l>>4
#pragma unroll
  for (int m = 1; m < 16; m <<= 1) {
#pragma unroll
    for (int j = 0; j < 4; ++j) {
      float ob = __shfl_xor(best[j], m, 64);
      float os = __shfl_xor(second[j], m, 64);
      int   oi = __shfl_xor(bidx[j], m, 64);
      if (ob < best[j]) {
        second[j] = fminf(os, best[j]);
        best[j] = ob; bidx[j] = oi;
      } else if (ob == best[j]) {
        bidx[j] = min(bidx[j], oi);
        second[j] = fminf(second[j], fminf(os, ob));  // dup min -> gap 0
      } else {
        second[j] = fminf(second[j], ob);
      }
    }
  }

  if (col == 0) {
#pragma unroll
    for (int j = 0; j < 4; ++j) {
      int lrow = w * 16 + ((l >> 4) << 2) + j;
      int r = blockIdx.x * 64 + lrow;
      sidx[lrow] = bidx[j];
      idx_out[r] = bidx[j];
      idx_f_out[r] = (float)bidx[j];
      atomicAdd(&cluster[bidx[j]], 1u);
      if (second[j] - best[j] < BAND) {
        uint p = atomicAdd(cnt, 1u);
        list[p] = (uint)r;
      }
    }
  }
  __syncthreads();

  // phase 2: zq write (in-order, coalesced) + f64 loss partial + dw atomics
  double ds = 0.0;
  const float4* z4 = (const float4*)z;
  const float4* e4 = (const float4*)emb;
  float4* zq4 = (float4*)out_zq;
  int blockrow = blockIdx.x * 64;
#pragma unroll
  for (int p = 0; p < 4; ++p) {
    int f = t + p * 256;               // 1024 float4s = 64 rows x 16
    int lrow = f >> 4, d4 = f & 15;
    int code = sidx[lrow];
    float4 zv = z4[(size_t)(blockrow + lrow) * 16 + d4];
    float4 ev = e4[code * 16 + d4];
    float dx = ev.x - zv.x, dy = ev.y - zv.y, dz = ev.z - zv.z, dw_ = ev.w - zv.w;
    float4 o;
    o.x = zv.x + dx; o.y = zv.y + dy; o.z = zv.z + dz; o.w = zv.w + dw_;
    zq4[(size_t)(blockrow + lrow) * 16 + d4] = o;
    float ss = dx * dx + dy * dy + dz * dz + dw_ * dw_;
    ds += (double)ss;
    float* dwp = dw + (size_t)code * DIMS + d4 * 4;
    atomic_add_f32_nr(dwp + 0, zv.x);
    atomic_add_f32_nr(dwp + 1, zv.y);
    atomic_add_f32_nr(dwp + 2, zv.z);
    atomic_add_f32_nr(dwp + 3, zv.w);
  }
#pragma unroll
  for (int o2 = 32; o2 > 0; o2 >>= 1) ds += __shfl_down(ds, o2, 64);
  if (l == 0) wred[w] = ds;
  __syncthreads();
  if (t == 0) sqpart[blockIdx.x] = (wred[0] + wred[1]) + (wred[2] + wred[3]);
}

// ---------------- K2: exact recheck of near-tie rows (numpy-f32 bit-exact) --
// Patches idx/cluster/zq/loss AND dw for rows whose index changes.
__global__ __launch_bounds__(256) void k2_recheck(const float* __restrict__ z,
                                                  const float* __restrict__ emb,
                                                  const float* __restrict__ ee,
                                                  const uint* __restrict__ cnt,
                                                  const uint* __restrict__ list,
                                                  int* __restrict__ idx_out,
                                                  float* __restrict__ idx_f_out,
                                                  float* __restrict__ out_zq,
                                                  uint* __restrict__ cluster,
                                                  float* __restrict__ dw,
                                                  double* __restrict__ corr) {
#pragma clang fp contract(off)
  __shared__ float zrow[DIMS];
  __shared__ float rv[256];
  __shared__ int   ri[256];
  __shared__ int   schg, sold, snew;
  int t = threadIdx.x;
  uint n = *cnt;
  double corrAcc = 0.0;
  const float4* e4 = (const float4*)emb;
  float4* zq4 = (float4*)out_zq;

  for (uint i = blockIdx.x; i < n; i += gridDim.x) {
    uint row = list[i];
    __syncthreads();
    if (t < 16)
      ((float4*)zrow)[t] = ((const float4*)(z + (size_t)row * DIMS))[t];
    __syncthreads();
    float zz = np_pairwise64_sq(zrow);
    float best = 3.4e38f; int bi = 0;
#pragma unroll
    for (int k4 = 0; k4 < 4; ++k4) {
      int c = t * 4 + k4;                      // ascending codes per thread
      const float* e = emb + (size_t)c * DIMS;
      float a = 0.f;
      for (int k = 0; k < DIMS; ++k) a = fmaf(zrow[k], e[k], a);
      float d = fmaf(-2.0f, a, zz + ee[c]);
      if (d < best) { best = d; bi = c; }
    }
    rv[t] = best; ri[t] = bi;
    __syncthreads();
    for (int s = 128; s > 0; s >>= 1) {
      if (t < s) {
        float ov = rv[t + s]; int oi = ri[t + s];
        if (ov < rv[t] || (ov == rv[t] && oi < ri[t])) { rv[t] = ov; ri[t] = oi; }
      }
      __syncthreads();
    }
    if (t == 0) {
      int old = idx_out[row];
      if (ri[0] != old) {
        atomicSub(&cluster[old], 1u);
        atomicAdd(&cluster[ri[0]], 1u);
        idx_out[row] = ri[0];
        idx_f_out[row] = (float)ri[0];
        schg = 1; sold = old; snew = ri[0];
      } else {
        schg = 0;
      }
    }
    __syncthreads();
    if (schg && t < 16) {
      float4 zv = make_float4(zrow[t*4], zrow[t*4+1], zrow[t*4+2], zrow[t*4+3]);
      float4 en = e4[snew * 16 + t];
      float4 eo = e4[sold * 16 + t];
      float dxn = en.x - zv.x, dyn = en.y - zv.y, dzn = en.z - zv.z, dwn = en.w - zv.w;
      float4 o;
      o.x = zv.x + dxn; o.y = zv.y + dyn; o.z = zv.z + dzn; o.w = zv.w + dwn;
      zq4[(size_t)row * 16 + t] = o;
      // dw patch: move this row's z from old code to new code
      float* dwo = dw + (size_t)sold * DIMS + t * 4;
      float* dwn2 = dw + (size_t)snew * DIMS + t * 4;
      atomic_add_f32_nr(dwo + 0, -zv.x); atomic_add_f32_nr(dwn2 + 0, zv.x);
      atomic_add_f32_nr(dwo + 1, -zv.y); atomic_add_f32_nr(dwn2 + 1, zv.y);
      atomic_add_f32_nr(dwo + 2, -zv.z); atomic_add_f32_nr(dwn2 + 2, zv.z);
      atomic_add_f32_nr(dwo + 3, -zv.w); atomic_add_f32_nr(dwn2 + 3, zv.w);
      float ssn = dxn * dxn + dyn * dyn + dzn * dzn + dwn * dwn;
      float dxo = eo.x - zv.x, dyo = eo.y - zv.y, dzo = eo.z - zv.z, dwo2 = eo.w - zv.w;
      float sso = dxo * dxo + dyo * dyo + dzo * dzo + dwo2 * dwo2;
      double cl = (double)ssn - (double)sso;
      cl += __shfl_xor(cl, 1, 64);
      cl += __shfl_xor(cl, 2, 64);
      cl += __shfl_xor(cl, 4, 64);
      cl += __shfl_xor(cl, 8, 64);
      if (t == 0) corrAcc += cl;
    }
  }
  if (t == 0) corr[blockIdx.x] = corrAcc;
}

// ---------------- KP': 1-block serial pass: ecs + perp + csb ---------------
// (prefix/cursor deleted -- the sort-based dw pipeline is gone)
__global__ __launch_bounds__(256) void kp(const uint* __restrict__ cluster,
                                          const float* __restrict__ ecs_in,
                                          float* __restrict__ csb,
                                          float* __restrict__ out) {
  __shared__ double red[256];
  int t = threadIdx.x;

  double nloc = 0.0, aloc = 0.0, bloc = 0.0;
  for (int c = t; c < NCODES; c += 256) {
    float cntf = (float)cluster[c];
    float ne = ecs_in[c] * DECAY + (1.0f - DECAY) * cntf;
    out[OFF_ECS + c] = ne;
    nloc += (double)ne;
    double p = (double)cntf / (double)N_ROWS;
    double pc = p < 1e-10 ? 1e-10 : p;
    bloc += pc;
    aloc += pc * log(pc);
  }

  red[t] = nloc; __syncthreads();
  for (int s = 128; s > 0; s >>= 1) { if (t < s) red[t] += red[t + s]; __syncthreads(); }
  double n = red[0]; __syncthreads();

  red[t] = bloc; __syncthreads();
  for (int s = 128; s > 0; s >>= 1) { if (t < s) red[t] += red[t + s]; __syncthreads(); }
  double B = red[0]; __syncthreads();

  red[t] = aloc; __syncthreads();
  for (int s = 128; s > 0; s >>= 1) { if (t < s) red[t] += red[t + s]; __syncthreads(); }
  double A = red[0]; __syncthreads();

  if (t == 0) {
    double ent = -(A / B - log(B));
    out[OFF_PERP] = (float)exp(ent);
  }

  float nf = (float)n;
  for (int c = t; c < NCODES; c += 256) {
    float ne = out[OFF_ECS + c];
    float cs = ((ne + EPSF) / (nf + (float)NCODES * EPSF)) * nf;
    csb[c] = cs < 0.01f ? 0.01f : cs;
  }
}

// ---------------- K4b: parallel finalize: ema_w + embedding + loss ---------
__global__ __launch_bounds__(256) void k4b_emb(const float* __restrict__ emaw_in,
                                               const float* __restrict__ dw,
                                               const float* __restrict__ csb,
                                               const double* __restrict__ sqpart,
                                               const double* __restrict__ corr,
                                               float* __restrict__ out) {
  int i = blockIdx.x * 256 + threadIdx.x;
  int c = i >> 6;
  float nw = emaw_in[i] * DECAY + (1.0f - DECAY) * dw[i];
  out[OFF_EMAW + i] = nw;
  out[OFF_EMB + i] = nw / csb[c];

  if (blockIdx.x == 0) {                      // block-uniform branch: loss
    __shared__ double red[256];
    int t = threadIdx.x;
    double sloc = 0.0;
    for (int k = t; k < 2048; k += 256) sloc += sqpart[k];
    for (int k = t; k < 1024; k += 256) sloc += corr[k];
    red[t] = sloc; __syncthreads();
    for (int s = 128; s > 0; s >>= 1) { if (t < s) red[t] += red[t + s]; __syncthreads(); }
    if (t == 0) {
      double M = red[0] / (double)((size_t)N_ROWS * DIMS);
      out[OFF_LOSS] = (float)(1.5 * M);       // 0.5*commitment + codebook
    }
  }
}

// ---------------- host ----------------
extern "C" void kernel_launch(void* const* d_in, const int* in_sizes, int n_in,
                              void* d_out, int out_size, void* d_ws, size_t ws_size,
                              hipStream_t stream) {
  const float* z    = (const float*)d_in[0];
  const float* emb  = (const float*)d_in[1];
  const float* ecs  = (const float*)d_in[2];
  const float* emaw = (const float*)d_in[3];
  float* out = (float*)d_out;

  char* ws = (char*)d_ws;
  uint*   cnt    = (uint*)   (ws + 0);          // 16 B
  int*    idxw   = (int*)    (ws + 16);         // 512 KB
  uint*   clus   = (uint*)   (ws + 524304);     // 4 KB
  float*  dw     = (float*)  (ws + 528416);     // 256 KB
  float*  ee     = (float*)  (ws + 790560);     // 4 KB
  float*  csb    = (float*)  (ws + 794656);     // 4 KB
  bf16x8* bsplit = (bf16x8*) (ws + 1335328);    // 256 KB
  uint*   rlist  = (uint*)   (ws + 1597472);    // 512 KB
  double* sqpart = (double*) (ws + 2646048);    // 16 KB (2048 k1 blocks)
  double* corr   = (double*) (ws + 2662432);    // 8 KB  (1024 k2 blocks)

  k0m<<<64, 256, 0, stream>>>(emb, ee, clus, cnt, bsplit, dw);
  k1_mfma<<<N_ROWS / 64, 256, 0, stream>>>(z, emb, bsplit, ee, idxw,
                                           out + OFF_IDX, out + OFF_ZQ,
                                           sqpart, clus, dw, cnt, rlist);
  k2_recheck<<<1024, 256, 0, stream>>>(z, emb, ee, cnt, rlist, idxw,
                                       out + OFF_IDX, out + OFF_ZQ, clus, dw,
                                       corr);
  kp<<<1, 256, 0, stream>>>(clus, ecs, csb, out);
  k4b_emb<<<256, 256, 0, stream>>>(emaw, dw, csb, sqpart, corr, out);
}

// Round 19
// 191.063 us; speedup vs baseline: 1.5086x; 1.5086x over previous
//
#include <hip/hip_runtime.h>
#include <hip/hip_bf16.h>
#include <math.h>

#define N_ROWS   131072   // 8*16384
#define DIMS     64
#define NCODES   1024
#define DECAY    0.99f
#define EPSF     1e-5f
#define BAND     2e-3f    // approx-gap band; eps_approx ~2e-4, 5x margin

// d_out layout (float32 elements)
#define OFF_ZQ    0
#define OFF_IDX   8388608
#define OFF_LOSS  8519680
#define OFF_PERP  8519681
#define OFF_EMB   8519682
#define OFF_ECS   8585218
#define OFF_EMAW  8586242

typedef unsigned int uint;
typedef short bf16x8 __attribute__((ext_vector_type(8)));
typedef float f32x4  __attribute__((ext_vector_type(4)));

__device__ __forceinline__ float atomic_add_f32(float* p, float v) {
  return __hip_atomic_fetch_add(p, v, __ATOMIC_RELAXED, __HIP_MEMORY_SCOPE_AGENT);
}

__device__ __forceinline__ unsigned short bf16_rne(float f) {
  uint u = __float_as_uint(f);
  uint r = u + 0x7fffu + ((u >> 16) & 1u);
  return (unsigned short)(r >> 16);
}
__device__ __forceinline__ float bf16_f32(unsigned short h) {
  return __uint_as_float(((uint)h) << 16);
}

// numpy pairwise_sum base case (n=64): 8 strided accumulators, tree combine.
__device__ __forceinline__ float np_pairwise64_sq(const float* v) {
#pragma clang fp contract(off)
  float r[8];
#pragma unroll
  for (int j = 0; j < 8; ++j) r[j] = v[j] * v[j];
#pragma unroll
  for (int i = 8; i < 64; i += 8)
#pragma unroll
    for (int j = 0; j < 8; ++j) r[j] += v[i + j] * v[i + j];
  return ((r[0] + r[1]) + (r[2] + r[3])) + ((r[4] + r[5]) + (r[6] + r[7]));
}

// ---------------- K0m: merged init + pack (grid 64) ------------------------
__global__ __launch_bounds__(256) void k0m(const float* __restrict__ emb,
                                           float* __restrict__ ee,
                                           uint* __restrict__ cluster,
                                           uint* __restrict__ cnt,
                                           bf16x8* __restrict__ bsplit,
                                           float* __restrict__ dw) {
  int T = blockIdx.x;
  int t = threadIdx.x;
  int gid = T * 256 + t;               // 16384 threads
  for (int i = gid; i < NCODES * DIMS; i += 16384) dw[i] = 0.0f;

  int l = t & 63;
  int slot = t >> 6;                   // 0..3 = (ktile<<1)|split
  int ktile = slot >> 1, split = slot & 1;
  int code = T * 16 + (l & 15);
  int k0 = ktile * 32 + ((l >> 4) << 3);
  const float* ep = emb + (size_t)code * DIMS + k0;
  float4 fa = *(const float4*)ep;
  float4 fb = *(const float4*)(ep + 4);
  float fs[8] = {fa.x, fa.y, fa.z, fa.w, fb.x, fb.y, fb.z, fb.w};
  bf16x8 v;
#pragma unroll
  for (int i = 0; i < 8; ++i) {
    unsigned short h = bf16_rne(fs[i]);
    if (split == 0) v[i] = (short)h;
    else            v[i] = (short)bf16_rne(fs[i] - bf16_f32(h));
  }
  bsplit[(size_t)((T * 2 + ktile) * 2 + split) * 64 + l] = v;

  if (t < 16) {
    int c = T * 16 + t;
    float ev[DIMS];
    const float4* e4 = (const float4*)(emb + (size_t)c * DIMS);
#pragma unroll
    for (int i = 0; i < 16; ++i) {
      float4 w = e4[i];
      ev[4*i] = w.x; ev[4*i+1] = w.y; ev[4*i+2] = w.z; ev[4*i+3] = w.w;
    }
    ee[c] = np_pairwise64_sq(ev);
  } else if (t < 32) {
    cluster[T * 16 + (t - 16)] = 0u;
  }
  if (T == 0 && t == 32) *cnt = 0u;
}

// ---------------- K1: MFMA argmin + fused zq/loss epilogue -----------------
// Round-13 structure (best measured, reproduced twice at ~191us total):
// prefetch issued AFTER the second barrier; 2 tiles per barrier pair.
// Epilogue: zq write in-order + f64 loss partial -> sqpart[block].
// Round-18 lesson: do NOT fold dw f32 atomics in here (8.4M atomics ->
// WRITE_SIZE 169MB, k1 226us; skewed hot codes serialize in L2).
__global__ __launch_bounds__(256) void k1_mfma(const float* __restrict__ z,
                                               const float* __restrict__ emb,
                                               const bf16x8* __restrict__ bsplit,
                                               const float* __restrict__ ee,
                                               int* __restrict__ idx_out,
                                               float* __restrict__ idx_f_out,
                                               float* __restrict__ out_zq,
                                               double* __restrict__ sqpart,
                                               uint* __restrict__ cluster,
                                               uint* __restrict__ cnt,
                                               uint* __restrict__ list) {
  __shared__ bf16x8 btile[2][256];     // 8KB: [tile parity][frag*64+lane]
  __shared__ float  eel[NCODES];       // 4KB
  __shared__ int    sidx[64];
  __shared__ double wred[4];
  int t = threadIdx.x;
  int l = t & 63;
  int w = t >> 6;
  int rowbase = blockIdx.x * 64 + w * 16;
  int arow = rowbase + (l & 15);
  int kq = (l >> 4) << 3;              // 0,8,16,24
  int col = l & 15;

  for (int i = t; i < NCODES; i += 256) eel[i] = ee[i];

  // A fragments: z row split into bf16 hi/mid, pre-scaled by -2 (exact).
  bf16x8 ahi[2], ami[2];
#pragma unroll
  for (int t2 = 0; t2 < 2; ++t2) {
    const float* zp = z + (size_t)arow * DIMS + t2 * 32 + kq;
    float4 fa = *(const float4*)zp;
    float4 fb = *(const float4*)(zp + 4);
    float fs[8] = {fa.x, fa.y, fa.z, fa.w, fb.x, fb.y, fb.z, fb.w};
#pragma unroll
    for (int i = 0; i < 8; ++i) {
      unsigned short h = bf16_rne(fs[i]);
      float m = fs[i] - bf16_f32(h);
      ahi[t2][i] = (short)bf16_rne(-2.0f * fs[i]);  // == -2*hi
      ami[t2][i] = (short)bf16_rne(-2.0f * m);      // == -2*mid
    }
  }

  float best[4]  = {3.4e38f, 3.4e38f, 3.4e38f, 3.4e38f};
  float second[4] = {3.4e38f, 3.4e38f, 3.4e38f, 3.4e38f};
  int   bidx[4] = {0, 0, 0, 0};

  // prefetch tiles 0,1 (frag w of each)
  bf16x8 vp0 = bsplit[(size_t)(0 * 4 + w) * 64 + l];
  bf16x8 vp1 = bsplit[(size_t)(1 * 4 + w) * 64 + l];

  for (int T = 0; T < 64; T += 2) {
    __syncthreads();                   // prior reads done; prefetch landed
    btile[0][w * 64 + l] = vp0;
    btile[1][w * 64 + l] = vp1;
    __syncthreads();                   // stores visible
    if (T + 2 < 64) {                  // issue NEXT prefetch *after* barrier:
      vp0 = bsplit[(size_t)((T + 2) * 4 + w) * 64 + l];  // in flight during
      vp1 = bsplit[(size_t)((T + 3) * 4 + w) * 64 + l];  // compute below
    }

#pragma unroll
    for (int u = 0; u < 2; ++u) {
      int code = (T + u) * 16 + col;
      float eeT = eel[code];
      bf16x8 bhi0 = btile[u][0 * 64 + l];
      bf16x8 bmi0 = btile[u][1 * 64 + l];
      bf16x8 bhi1 = btile[u][2 * 64 + l];
      bf16x8 bmi1 = btile[u][3 * 64 + l];

      f32x4 acc = {eeT, eeT, eeT, eeT};  // C-seed: s = ee - 2*dot
      acc = __builtin_amdgcn_mfma_f32_16x16x32_bf16(ahi[0], bhi0, acc, 0, 0, 0);
      acc = __builtin_amdgcn_mfma_f32_16x16x32_bf16(ahi[1], bhi1, acc, 0, 0, 0);
      acc = __builtin_amdgcn_mfma_f32_16x16x32_bf16(ahi[0], bmi0, acc, 0, 0, 0);
      acc = __builtin_amdgcn_mfma_f32_16x16x32_bf16(ahi[1], bmi1, acc, 0, 0, 0);
      acc = __builtin_amdgcn_mfma_f32_16x16x32_bf16(ami[0], bhi0, acc, 0, 0, 0);
      acc = __builtin_amdgcn_mfma_f32_16x16x32_bf16(ami[1], bhi1, acc, 0, 0, 0);

#pragma unroll
      for (int j = 0; j < 4; ++j) {
        float s = acc[j];
        bool lt = s < best[j];
        second[j] = lt ? best[j] : fminf(second[j], s);
        best[j]   = lt ? s : best[j];
        bidx[j]   = lt ? code : bidx[j];
      }
    }
  }

  // reduce (best, second, idx) across the 16 lanes sharing l>>4
#pragma unroll
  for (int m = 1; m < 16; m <<= 1) {
#pragma unroll
    for (int j = 0; j < 4; ++j) {
      float ob = __shfl_xor(best[j], m, 64);
      float os = __shfl_xor(second[j], m, 64);
      int   oi = __shfl_xor(bidx[j], m, 64);
      if (ob < best[j]) {
        second[j] = fminf(os, best[j]);
        best[j] = ob; bidx[j] = oi;
      } else if (ob == best[j]) {
        bidx[j] = min(bidx[j], oi);
        second[j] = fminf(second[j], fminf(os, ob));  // dup min -> gap 0
      } else {
        second[j] = fminf(second[j], ob);
      }
    }
  }

  if (col == 0) {
#pragma unroll
    for (int j = 0; j < 4; ++j) {
      int lrow = w * 16 + ((l >> 4) << 2) + j;
      int r = blockIdx.x * 64 + lrow;
      sidx[lrow] = bidx[j];
      idx_out[r] = bidx[j];
      idx_f_out[r] = (float)bidx[j];
      atomicAdd(&cluster[bidx[j]], 1u);
      if (second[j] - best[j] < BAND) {
        uint p = atomicAdd(cnt, 1u);
        list[p] = (uint)r;
      }
    }
  }
  __syncthreads();

  // phase 2: zq write (in-order, coalesced) + f64 loss partial
  double ds = 0.0;
  const float4* z4 = (const float4*)z;
  const float4* e4 = (const float4*)emb;
  float4* zq4 = (float4*)out_zq;
  int blockrow = blockIdx.x * 64;
#pragma unroll
  for (int p = 0; p < 4; ++p) {
    int f = t + p * 256;               // 1024 float4s = 64 rows x 16
    int lrow = f >> 4, d4 = f & 15;
    int code = sidx[lrow];
    float4 zv = z4[(size_t)(blockrow + lrow) * 16 + d4];
    float4 ev = e4[code * 16 + d4];
    float dx = ev.x - zv.x, dy = ev.y - zv.y, dz = ev.z - zv.z, dw_ = ev.w - zv.w;
    float4 o;
    o.x = zv.x + dx; o.y = zv.y + dy; o.z = zv.z + dz; o.w = zv.w + dw_;
    zq4[(size_t)(blockrow + lrow) * 16 + d4] = o;
    float ss = dx * dx + dy * dy + dz * dz + dw_ * dw_;
    ds += (double)ss;
  }
#pragma unroll
  for (int o2 = 32; o2 > 0; o2 >>= 1) ds += __shfl_down(ds, o2, 64);
  if (l == 0) wred[w] = ds;
  __syncthreads();
  if (t == 0) sqpart[blockIdx.x] = (wred[0] + wred[1]) + (wred[2] + wred[3]);
}

// ---------------- K2: exact recheck of near-tie rows (numpy-f32 bit-exact) --
// Patches idx/cluster AND zq/loss for rows whose index changes; per-block
// f64 loss correction -> corr[blockIdx] (plain store, summed in k4b).
__global__ __launch_bounds__(256) void k2_recheck(const float* __restrict__ z,
                                                  const float* __restrict__ emb,
                                                  const float* __restrict__ ee,
                                                  const uint* __restrict__ cnt,
                                                  const uint* __restrict__ list,
                                                  int* __restrict__ idx_out,
                                                  float* __restrict__ idx_f_out,
                                                  float* __restrict__ out_zq,
                                                  uint* __restrict__ cluster,
                                                  double* __restrict__ corr) {
#pragma clang fp contract(off)
  __shared__ float zrow[DIMS];
  __shared__ float rv[256];
  __shared__ int   ri[256];
  __shared__ int   schg, sold, snew;
  int t = threadIdx.x;
  uint n = *cnt;
  double corrAcc = 0.0;
  const float4* e4 = (const float4*)emb;
  float4* zq4 = (float4*)out_zq;

  for (uint i = blockIdx.x; i < n; i += gridDim.x) {
    uint row = list[i];
    __syncthreads();
    if (t < 16)
      ((float4*)zrow)[t] = ((const float4*)(z + (size_t)row * DIMS))[t];
    __syncthreads();
    float zz = np_pairwise64_sq(zrow);
    float best = 3.4e38f; int bi = 0;
#pragma unroll
    for (int k4 = 0; k4 < 4; ++k4) {
      int c = t * 4 + k4;                      // ascending codes per thread
      const float* e = emb + (size_t)c * DIMS;
      float a = 0.f;
      for (int k = 0; k < DIMS; ++k) a = fmaf(zrow[k], e[k], a);
      float d = fmaf(-2.0f, a, zz + ee[c]);
      if (d < best) { best = d; bi = c; }
    }
    rv[t] = best; ri[t] = bi;
    __syncthreads();
    for (int s = 128; s > 0; s >>= 1) {
      if (t < s) {
        float ov = rv[t + s]; int oi = ri[t + s];
        if (ov < rv[t] || (ov == rv[t] && oi < ri[t])) { rv[t] = ov; ri[t] = oi; }
      }
      __syncthreads();
    }
    if (t == 0) {
      int old = idx_out[row];
      if (ri[0] != old) {
        atomicSub(&cluster[old], 1u);
        atomicAdd(&cluster[ri[0]], 1u);
        idx_out[row] = ri[0];
        idx_f_out[row] = (float)ri[0];
        schg = 1; sold = old; snew = ri[0];
      } else {
        schg = 0;
      }
    }
    __syncthreads();
    if (schg && t < 16) {
      float4 zv = make_float4(zrow[t*4], zrow[t*4+1], zrow[t*4+2], zrow[t*4+3]);
      float4 en = e4[snew * 16 + t];
      float4 eo = e4[sold * 16 + t];
      float dxn = en.x - zv.x, dyn = en.y - zv.y, dzn = en.z - zv.z, dwn = en.w - zv.w;
      float4 o;
      o.x = zv.x + dxn; o.y = zv.y + dyn; o.z = zv.z + dzn; o.w = zv.w + dwn;
      zq4[(size_t)row * 16 + t] = o;
      float ssn = dxn * dxn + dyn * dyn + dzn * dzn + dwn * dwn;
      float dxo = eo.x - zv.x, dyo = eo.y - zv.y, dzo = eo.z - zv.z, dwo = eo.w - zv.w;
      float sso = dxo * dxo + dyo * dyo + dzo * dzo + dwo * dwo;
      double cl = (double)ssn - (double)sso;
      cl += __shfl_xor(cl, 1, 64);
      cl += __shfl_xor(cl, 2, 64);
      cl += __shfl_xor(cl, 4, 64);
      cl += __shfl_xor(cl, 8, 64);
      if (t == 0) corrAcc += cl;
    }
  }
  if (t == 0) corr[blockIdx.x] = corrAcc;
}

// ---------------- KP: fused 1-block serial pass ----------------------------
__global__ __launch_bounds__(256) void kp(const uint* __restrict__ cluster,
                                          const float* __restrict__ ecs_in,
                                          uint* __restrict__ starts,
                                          uint* __restrict__ cursor,
                                          float* __restrict__ csb,
                                          float* __restrict__ out) {
  __shared__ uint a[256], b[256];
  __shared__ double red[256];
  int t = threadIdx.x;

  uint c0 = cluster[t*4+0], c1 = cluster[t*4+1], c2 = cluster[t*4+2], c3 = cluster[t*4+3];
  uint s4 = c0 + c1 + c2 + c3;
  a[t] = s4;
  __syncthreads();
  uint* src = a; uint* dst = b;
  for (int off = 1; off < 256; off <<= 1) {
    dst[t] = src[t] + ((t >= off) ? src[t - off] : 0u);
    __syncthreads();
    uint* tmp = src; src = dst; dst = tmp;
  }
  uint base = (t > 0) ? src[t-1] : 0u;
  uint p0 = base, p1 = p0 + c0, p2 = p1 + c1, p3 = p2 + c2;
  starts[t*4+0] = p0; starts[t*4+1] = p1; starts[t*4+2] = p2; starts[t*4+3] = p3;
  cursor[t*4+0] = p0; cursor[t*4+1] = p1; cursor[t*4+2] = p2; cursor[t*4+3] = p3;
  if (t == 255) starts[NCODES] = src[255];
  __syncthreads();

  double nloc = 0.0, aloc = 0.0, bloc = 0.0;
  for (int c = t; c < NCODES; c += 256) {
    float cntf = (float)cluster[c];
    float ne = ecs_in[c] * DECAY + (1.0f - DECAY) * cntf;
    out[OFF_ECS + c] = ne;
    nloc += (double)ne;
    double p = (double)cntf / (double)N_ROWS;
    double pc = p < 1e-10 ? 1e-10 : p;
    bloc += pc;
    aloc += pc * log(pc);
  }

  red[t] = nloc; __syncthreads();
  for (int s = 128; s > 0; s >>= 1) { if (t < s) red[t] += red[t + s]; __syncthreads(); }
  double n = red[0]; __syncthreads();

  red[t] = bloc; __syncthreads();
  for (int s = 128; s > 0; s >>= 1) { if (t < s) red[t] += red[t + s]; __syncthreads(); }
  double B = red[0]; __syncthreads();

  red[t] = aloc; __syncthreads();
  for (int s = 128; s > 0; s >>= 1) { if (t < s) red[t] += red[t + s]; __syncthreads(); }
  double A = red[0]; __syncthreads();

  if (t == 0) {
    double ent = -(A / B - log(B));
    out[OFF_PERP] = (float)exp(ent);
  }

  float nf = (float)n;
  for (int c = t; c < NCODES; c += 256) {
    float ne = out[OFF_ECS + c];
    float cs = ((ne + EPSF) / (nf + (float)NCODES * EPSF)) * nf;
    csb[c] = cs < 0.01f ? 0.01f : cs;
  }
}

// ---------------- K3c: scatter row ids + codes into sorted positions -------
__global__ __launch_bounds__(256) void k3c_scatter(const int* __restrict__ idx,
                                                   uint* __restrict__ cursor,
                                                   uint* __restrict__ rowids,
                                                   int* __restrict__ codes) {
  int row = blockIdx.x * 256 + threadIdx.x;
  int code = idx[row];
  uint pos = atomicAdd(&cursor[code], 1u);
  rowids[pos] = (uint)row;
  codes[pos] = code;
}

// ---------------- K3d: POSITION-balanced dw-only pass ----------------------
__global__ __launch_bounds__(256) void k3d_dw(const float* __restrict__ z,
                                              const uint* __restrict__ rowids,
                                              const int* __restrict__ codes,
                                              float* __restrict__ dw) {
  int lane = threadIdx.x & 63, w = threadIdx.x >> 6;
  int base = blockIdx.x * 128 + w * 32;

  int cur = codes[base];                      // wave-uniform
  float acc = 0.f;
  for (int i = 0; i < 32; ++i) {
    int p = base + i;
    uint r = rowids[p];                       // wave-uniform s_load
    int c = codes[p];                         // wave-uniform s_load
    if (c != cur) {                           // uniform branch
      atomic_add_f32(&dw[cur * DIMS + lane], acc);
      acc = 0.f; cur = c;
    }
    acc += z[(size_t)r * DIMS + lane];        // 256B coalesced
  }
  atomic_add_f32(&dw[cur * DIMS + lane], acc);
}

// ---------------- K4b: parallel finalize: ema_w + embedding + loss ---------
__global__ __launch_bounds__(256) void k4b_emb(const float* __restrict__ emaw_in,
                                               const float* __restrict__ dw,
                                               const float* __restrict__ csb,
                                               const double* __restrict__ sqpart,
                                               const double* __restrict__ corr,
                                               float* __restrict__ out) {
  int i = blockIdx.x * 256 + threadIdx.x;
  int c = i >> 6;
  float nw = emaw_in[i] * DECAY + (1.0f - DECAY) * dw[i];
  out[OFF_EMAW + i] = nw;
  out[OFF_EMB + i] = nw / csb[c];

  if (blockIdx.x == 0) {                      // block-uniform branch: loss
    __shared__ double red[256];
    int t = threadIdx.x;
    double sloc = 0.0;
    for (int k = t; k < 2048; k += 256) sloc += sqpart[k];
    for (int k = t; k < 1024; k += 256) sloc += corr[k];
    red[t] = sloc; __syncthreads();
    for (int s = 128; s > 0; s >>= 1) { if (t < s) red[t] += red[t + s]; __syncthreads(); }
    if (t == 0) {
      double M = red[0] / (double)((size_t)N_ROWS * DIMS);
      out[OFF_LOSS] = (float)(1.5 * M);       // 0.5*commitment + codebook
    }
  }
}

// ---------------- host ----------------
extern "C" void kernel_launch(void* const* d_in, const int* in_sizes, int n_in,
                              void* d_out, int out_size, void* d_ws, size_t ws_size,
                              hipStream_t stream) {
  const float* z    = (const float*)d_in[0];
  const float* emb  = (const float*)d_in[1];
  const float* ecs  = (const float*)d_in[2];
  const float* emaw = (const float*)d_in[3];
  float* out = (float*)d_out;

  char* ws = (char*)d_ws;
  uint*   cnt    = (uint*)   (ws + 0);          // 16 B
  int*    idxw   = (int*)    (ws + 16);         // 512 KB
  uint*   clus   = (uint*)   (ws + 524304);     // 4 KB
  float*  dw     = (float*)  (ws + 528416);     // 256 KB
  float*  ee     = (float*)  (ws + 790560);     // 4 KB
  float*  csb    = (float*)  (ws + 794656);     // 4 KB
  uint*   starts = (uint*)   (ws + 798752);     // 8 KB
  uint*   cursor = (uint*)   (ws + 806944);     // 4 KB
  uint*   rowids = (uint*)   (ws + 811040);     // 512 KB
  bf16x8* bsplit = (bf16x8*) (ws + 1335328);    // 256 KB
  uint*   rlist  = (uint*)   (ws + 1597472);    // 512 KB
  int*    codes  = (int*)    (ws + 2121760);    // 512 KB
  double* sqpart = (double*) (ws + 2646048);    // 16 KB (2048 k1 blocks)
  double* corr   = (double*) (ws + 2662432);    // 8 KB  (1024 k2 blocks)

  k0m<<<64, 256, 0, stream>>>(emb, ee, clus, cnt, bsplit, dw);
  k1_mfma<<<N_ROWS / 64, 256, 0, stream>>>(z, emb, bsplit, ee, idxw,
                                           out + OFF_IDX, out + OFF_ZQ,
                                           sqpart, clus, cnt, rlist);
  k2_recheck<<<1024, 256, 0, stream>>>(z, emb, ee, cnt, rlist, idxw,
                                       out + OFF_IDX, out + OFF_ZQ, clus, corr);
  kp<<<1, 256, 0, stream>>>(clus, ecs, starts, cursor, csb, out);
  k3c_scatter<<<N_ROWS / 256, 256, 0, stream>>>(idxw, cursor, rowids, codes);
  k3d_dw<<<N_ROWS / 128, 256, 0, stream>>>(z, rowids, codes, dw);
  k4b_emb<<<256, 256, 0, stream>>>(emaw, dw, csb, sqpart, corr, out);
}